// Round 1
// baseline (65.907 us; speedup 1.0000x reference)
//
#include <hip/hip_runtime.h>
#include <math.h>

#define MGEMM 3072   // 512 h-groups * 6 kept m-rows
#define NGEMM 512
#define KGEMM 512
#define NJ    6      // j = 2..7
#define MK    (MGEMM * KGEMM)
#define MN    (MGEMM * NGEMM)

typedef __attribute__((ext_vector_type(8))) __bf16 bf16x8;
typedef __attribute__((ext_vector_type(4))) float  f32x4;

__device__ __forceinline__ unsigned short f2bf(float f) {
  union { float f; unsigned u; } v; v.f = f;
  unsigned r = v.u + 0x7fffu + ((v.u >> 16) & 1u);   // RNE
  return (unsigned short)(r >> 16);
}
__device__ __forceinline__ float bf2f(unsigned short s) {
  union { unsigned u; float f; } v; v.u = ((unsigned)s) << 16;
  return v.f;
}

// 8-point DCT-II matrix (orthonormal), rows m, cols i.
__device__ const float DBC[8][8] = {
  { 0.35355339f,  0.35355339f,  0.35355339f,  0.35355339f,  0.35355339f,  0.35355339f,  0.35355339f,  0.35355339f},
  { 0.49039264f,  0.41573481f,  0.27778512f,  0.09754516f, -0.09754516f, -0.27778512f, -0.41573481f, -0.49039264f},
  { 0.46193977f,  0.19134172f, -0.19134172f, -0.46193977f, -0.46193977f, -0.19134172f,  0.19134172f,  0.46193977f},
  { 0.41573481f, -0.09754516f, -0.49039264f, -0.27778512f,  0.27778512f,  0.49039264f,  0.09754516f, -0.41573481f},
  { 0.35355339f, -0.35355339f, -0.35355339f,  0.35355339f,  0.35355339f, -0.35355339f, -0.35355339f,  0.35355339f},
  { 0.27778512f, -0.49039264f,  0.09754516f,  0.41573481f, -0.41573481f, -0.09754516f,  0.49039264f, -0.27778512f},
  { 0.19134172f, -0.46193977f,  0.46193977f, -0.19134172f, -0.19134172f,  0.46193977f, -0.46193977f,  0.19134172f},
  { 0.09754516f, -0.27778512f,  0.41573481f, -0.49039264f,  0.49039264f, -0.41573481f,  0.27778512f, -0.09754516f}
};

// ---------------- 1) Dw table: dw[k][w] = bf16( scale(k) * cos(pi*(2w+1)*k/1024) )
__global__ __launch_bounds__(256) void build_dw(unsigned short* __restrict__ dw) {
  int idx = blockIdx.x * 256 + threadIdx.x;       // 512*512
  int k = idx >> 9, w = idx & 511;
  double scale = (k == 0) ? 0.04419417382415922 : 0.0625;  // sqrt(1/512), sqrt(2/512)
  double c = cos(M_PI * (2.0 * w + 1.0) * (double)k / 1024.0);
  dw[idx] = f2bf((float)(c * scale));
}

// ---------------- 2) pack: q=floor(255x), apply Db rows m=2..7, split by j=2..7
// zc[j-2][h*6+(m-2)][w] bf16, each matrix 3072x512 contiguous.
__global__ __launch_bounds__(256) void pack_z(const float* __restrict__ x,
                                              unsigned short* __restrict__ zc) {
  const int h  = blockIdx.x;                 // 0..511
  const int t  = threadIdx.x;                // 0..255
  const int c0 = blockIdx.y * 2048 + t * 8;  // 8 consecutive cols = one w, all j
  const float* xb = x + (size_t)(h * 8) * 4096 + c0;
  float q[8][8];
#pragma unroll
  for (int i = 0; i < 8; ++i) {
    float4 a = *reinterpret_cast<const float4*>(xb + (size_t)i * 4096);
    float4 b = *reinterpret_cast<const float4*>(xb + (size_t)i * 4096 + 4);
    q[i][0] = floorf(a.x * 255.0f); q[i][1] = floorf(a.y * 255.0f);
    q[i][2] = floorf(a.z * 255.0f); q[i][3] = floorf(a.w * 255.0f);
    q[i][4] = floorf(b.x * 255.0f); q[i][5] = floorf(b.y * 255.0f);
    q[i][6] = floorf(b.z * 255.0f); q[i][7] = floorf(b.w * 255.0f);
  }
  const int w0 = c0 >> 3;
#pragma unroll
  for (int m = 2; m < 8; ++m) {
    const size_t rowoff = (size_t)(h * 6 + (m - 2)) * KGEMM + w0;
#pragma unroll
    for (int j = 2; j < 8; ++j) {
      float s = 0.0f;
#pragma unroll
      for (int i = 0; i < 8; ++i) s = fmaf(DBC[m][i], q[i][j], s);
      zc[(size_t)(j - 2) * MK + rowoff] = f2bf(s);   // per (m,j): 64 lanes write 128B contiguous
    }
  }
}

// ---------------- 3) GEMM: Cc[j][rc][k] = sum_w zc[j][rc][w] * Dw[k][w]
// A: [3072][512] bf16 row-major. B stored as Dw[k][w] row-major == B-operand [n][kdim].
__device__ __forceinline__ void gload16(const unsigned short* g, unsigned short* l) {
  __builtin_amdgcn_global_load_lds(
      (__attribute__((address_space(1))) void*)(g),
      (__attribute__((address_space(3))) void*)(l),
      16, 0, 0);
}

__global__ __launch_bounds__(256) void gemm_dct(const unsigned short* __restrict__ zc,
                                                const unsigned short* __restrict__ dw,
                                                unsigned short* __restrict__ cc) {
  const int mt = blockIdx.x;   // 0..23
  const int nt = blockIdx.y;   // 0..3
  const int jj = blockIdx.z;   // 0..5
  __shared__ unsigned short Ash[128 * 64];
  __shared__ unsigned short Bsh[128 * 64];
  const unsigned short* Abase = zc + (size_t)jj * MK;

  const int tid  = threadIdx.x;
  const int lane = tid & 63;
  const int wv   = tid >> 6;
  const int wm   = wv & 1;    // wave row (64)
  const int wn   = wv >> 1;   // wave col (64)

  f32x4 acc[4][4] = {};

  for (int kko = 0; kko < 8; ++kko) {       // K = 512, BK = 64
    __syncthreads();
#pragma unroll
    for (int q = 0; q < 4; ++q) {
      const int o    = wv * 4096 + q * 1024 + lane * 16;  // byte offset in 16KB tile
      const int row  = o >> 7;                            // 128B per row (64 bf16)
      const int ecol = (o & 127) >> 1;
      gload16(Abase + (size_t)(mt * 128 + row) * 512 + kko * 64 + ecol, Ash + (o >> 1));
      gload16(dw    + (size_t)(nt * 128 + row) * 512 + kko * 64 + ecol, Bsh + (o >> 1));
    }
    __syncthreads();
#pragma unroll
    for (int ks = 0; ks < 2; ++ks) {        // two K=32 MFMA steps
      const int ko = ks * 32 + (lane >> 4) * 8;
      bf16x8 af[4], bf[4];
#pragma unroll
      for (int f = 0; f < 4; ++f) {
        af[f] = *reinterpret_cast<const bf16x8*>(Ash + (wm * 64 + f * 16 + (lane & 15)) * 64 + ko);
        bf[f] = *reinterpret_cast<const bf16x8*>(Bsh + (wn * 64 + f * 16 + (lane & 15)) * 64 + ko);
      }
#pragma unroll
      for (int fm = 0; fm < 4; ++fm)
#pragma unroll
        for (int fn = 0; fn < 4; ++fn)
          acc[fm][fn] = __builtin_amdgcn_mfma_f32_16x16x32_bf16(af[fm], bf[fn], acc[fm][fn], 0, 0, 0);
    }
  }

  // epilogue: C/D layout col=lane&15, row=(lane>>4)*4+p  [m89-verified]
  unsigned short* Cbase = cc + (size_t)jj * MN;
  const int r0 = mt * 128 + wm * 64;
  const int c0 = nt * 128 + wn * 64;
#pragma unroll
  for (int fm = 0; fm < 4; ++fm)
#pragma unroll
    for (int fn = 0; fn < 4; ++fn)
#pragma unroll
      for (int p = 0; p < 4; ++p) {
        const int r = r0 + fm * 16 + (lane >> 4) * 4 + p;
        const int c = c0 + fn * 16 + (lane & 15);
        Cbase[(size_t)r * NGEMM + c] = f2bf(acc[fm][fn][p]);
      }
}

// ---------------- 4) interleave + mask zero-fill: out[r, k*8+j]
__global__ __launch_bounds__(256) void interleave(const unsigned short* __restrict__ cc,
                                                  float* __restrict__ out) {
  const int t  = blockIdx.x * 256 + threadIdx.x;   // 4096*4096/4 threads
  const int r  = t >> 10;
  const int c4 = (t & 1023) << 2;                  // first of 4 consecutive cols
  const int m  = r & 7;
  float4 v = make_float4(0.f, 0.f, 0.f, 0.f);
  if (m >= 2) {
    const int k = c4 >> 3;
    const size_t rowoff = (size_t)((r >> 3) * 6 + (m - 2)) * NGEMM + k;
    const int jbase = c4 & 4;                      // 0 -> j=0..3, 4 -> j=4..7
    float vv[4];
#pragma unroll
    for (int e = 0; e < 4; ++e) {
      const int j = jbase + e;
      vv[e] = (j >= 2) ? bf2f(cc[(size_t)(j - 2) * MN + rowoff]) : 0.0f;
    }
    v = make_float4(vv[0], vv[1], vv[2], vv[3]);
  }
  *reinterpret_cast<float4*>(out + (size_t)t * 4) = v;
}

extern "C" void kernel_launch(void* const* d_in, const int* in_sizes, int n_in,
                              void* d_out, int out_size, void* d_ws, size_t ws_size,
                              hipStream_t stream) {
  const float* x = (const float*)d_in[0];
  float* out = (float*)d_out;
  char* ws = (char*)d_ws;

  unsigned short* dw = (unsigned short*)ws;                                  // 512 KB
  unsigned short* zc = (unsigned short*)(ws + 524288);                       // 18.87 MB
  unsigned short* cc = (unsigned short*)(ws + 524288 + (size_t)NJ * MK * 2); // 18.87 MB

  build_dw<<<1024, 256, 0, stream>>>(dw);
  pack_z<<<dim3(512, 2), 256, 0, stream>>>(x, zc);
  gemm_dct<<<dim3(24, 4, 6), 256, 0, stream>>>(zc, dw, cc);
  interleave<<<16384, 256, 0, stream>>>(cc, out);
}